// Round 1
// baseline (148.163 us; speedup 1.0000x reference)
//
#include <hip/hip_runtime.h>
#include <math.h>

#define HW     16384
#define CDIM   10
#define NPIX   131072        // B*H*W
#define NPLANE 1310720       // B*C*H*W
#define BN_N   131072.0f
#define EPS_BN 1e-5f

__device__ __forceinline__ float sigf(float x) { return 1.0f / (1.0f + __expf(-x)); }
__device__ __forceinline__ float tanh_fast(float x) {
    x = fminf(fmaxf(x, -15.0f), 15.0f);
    float e = __expf(2.0f * x);
    return (e - 1.0f) / (e + 1.0f);
}
__device__ __forceinline__ float wred(float v) {
#pragma unroll
    for (int o = 32; o; o >>= 1) v += __shfl_down(v, o, 64);
    return v;
}

// Kernel A: node0 (GRU0), comp_att, and BN1 stats of y1 = W_r1 @ [f1, (h1+h2)*att]
__global__ __launch_bounds__(256) void kernA(
    const float* __restrict__ f0, const float* __restrict__ f1,
    const float* __restrict__ h0, const float* __restrict__ h1, const float* __restrict__ h2,
    const float* __restrict__ W_att, const float* __restrict__ b_att,
    const float* __restrict__ W_r1,
    const float* __restrict__ Wg0, const float* __restrict__ bg0, const float* __restrict__ Wc0,
    float* __restrict__ node0, float* __restrict__ att_out, float* __restrict__ stats1)
{
    __shared__ float sW1[400], sWatt[20], sWg[40], sWc[200];
    __shared__ float sPart[4 * 40];   // per-wave partials: [wave][40]
    const int tid = threadIdx.x;
    for (int i = tid; i < 400; i += 256) sW1[i] = W_r1[i];
    for (int i = tid; i < 200; i += 256) sWc[i] = Wc0[i];
    if (tid < 20) sWatt[tid] = W_att[tid];
    if (tid < 40) sWg[tid] = Wg0[tid];
    __syncthreads();
    const float batt = b_att[0], bg_r = bg0[0], bg_u = bg0[1];
    const int p = blockIdx.x * 256 + tid;
    const int b = p >> 14, s = p & 16383;
    const int base = b * (CDIM * HW) + s;
    const int wave = tid >> 6, lane = tid & 63;

    float vh1[10], vh2[10], vf1[10];
#pragma unroll
    for (int c = 0; c < 10; c++) {
        vh1[c] = h1[base + c * HW];
        vh2[c] = h2[base + c * HW];
        vf1[c] = f1[base + c * HW];
    }
    // comp_att
    float z = batt;
#pragma unroll
    for (int c = 0; c < 10; c++) z += sWatt[c] * vh1[c] + sWatt[10 + c] * vh2[c];
    const float att = sigf(z);
    att_out[p] = att;

    // x = [f1, (h1+h2)*att]; y1 = W_r1 @ x (stats only)
    float x[20];
#pragma unroll
    for (int c = 0; c < 10; c++) { x[c] = vf1[c]; x[10 + c] = (vh1[c] + vh2[c]) * att; }
#pragma unroll
    for (int o = 0; o < 20; o++) {
        float acc = 0.0f;
#pragma unroll
        for (int i = 0; i < 20; i++) acc = fmaf(sW1[o * 20 + i], x[i], acc);
        float q = acc * acc;
        float rs = wred(acc);
        float rq = wred(q);
        if (lane == 0) { sPart[wave * 40 + o] = rs; sPart[wave * 40 + 20 + o] = rq; }
    }
    __syncthreads();
    if (tid < 40) {
        float t = sPart[tid] + sPart[40 + tid] + sPart[80 + tid] + sPart[120 + tid];
        atomicAdd(&stats1[tid], t);
    }

    // node0 = GRU0(x=h0, h=f0)
    float vf0[10], vh0[10];
#pragma unroll
    for (int c = 0; c < 10; c++) { vf0[c] = f0[base + c * HW]; vh0[c] = h0[base + c * HW]; }
    float g0 = bg_r, g1 = bg_u;
#pragma unroll
    for (int i = 0; i < 10; i++) {
        g0 += sWg[i] * vh0[i] + sWg[10 + i] * vf0[i];
        g1 += sWg[20 + i] * vh0[i] + sWg[30 + i] * vf0[i];
    }
    const float r = sigf(g0), u = sigf(g1);
#pragma unroll
    for (int o = 0; o < 10; o++) {
        float acc = 0.0f;
#pragma unroll
        for (int i = 0; i < 10; i++) acc = fmaf(sWc[o * 20 + i], vh0[i], acc);
#pragma unroll
        for (int i = 0; i < 10; i++) acc = fmaf(sWc[o * 20 + 10 + i], r * vf0[i], acc);
        node0[base + o * HW] = (1.0f - u) * vf0[o] + u * tanh_fast(acc);
    }
}

// Kernel C: finalize BN1, recompute y1, BN1+ReLU, y2 = W_r2 @ x2, BN2 stats
__global__ __launch_bounds__(256) void kernC(
    const float* __restrict__ f1, const float* __restrict__ h1, const float* __restrict__ h2,
    const float* __restrict__ att_in,
    const float* __restrict__ W_r1, const float* __restrict__ g_r1, const float* __restrict__ be_r1,
    const float* __restrict__ W_r2,
    const float* __restrict__ stats1, float* __restrict__ y2out, float* __restrict__ stats2)
{
    __shared__ float sW1[400], sW2[200], sA[20], sB[20];
    __shared__ float sPart[4 * 20];
    const int tid = threadIdx.x;
    for (int i = tid; i < 400; i += 256) sW1[i] = W_r1[i];
    for (int i = tid; i < 200; i += 256) sW2[i] = W_r2[i];
    if (tid < 20) {
        float sm = stats1[tid], sq = stats1[20 + tid];
        float mean = sm * (1.0f / BN_N);
        float var = sq * (1.0f / BN_N) - mean * mean;
        float a = g_r1[tid] * rsqrtf(var + EPS_BN);
        sA[tid] = a;
        sB[tid] = be_r1[tid] - mean * a;
    }
    __syncthreads();
    const int p = blockIdx.x * 256 + tid;
    const int b = p >> 14, s = p & 16383;
    const int base = b * (CDIM * HW) + s;
    const int wave = tid >> 6, lane = tid & 63;

    float vh1[10], vh2[10], vf1[10];
#pragma unroll
    for (int c = 0; c < 10; c++) {
        vh1[c] = h1[base + c * HW];
        vh2[c] = h2[base + c * HW];
        vf1[c] = f1[base + c * HW];
    }
    const float att = att_in[p];
    float x[20];
#pragma unroll
    for (int c = 0; c < 10; c++) { x[c] = vf1[c]; x[10 + c] = (vh1[c] + vh2[c]) * att; }
    float x2[20];
#pragma unroll
    for (int o = 0; o < 20; o++) {
        float acc = 0.0f;
#pragma unroll
        for (int i = 0; i < 20; i++) acc = fmaf(sW1[o * 20 + i], x[i], acc);
        x2[o] = fmaxf(fmaf(sA[o], acc, sB[o]), 0.0f);
    }
    const int base2 = b * (10 * HW) + s;
#pragma unroll
    for (int o = 0; o < 10; o++) {
        float acc = 0.0f;
#pragma unroll
        for (int i = 0; i < 20; i++) acc = fmaf(sW2[o * 20 + i], x2[i], acc);
        y2out[base2 + o * HW] = acc;
        float q = acc * acc;
        float rs = wred(acc);
        float rq = wred(q);
        if (lane == 0) { sPart[wave * 20 + o] = rs; sPart[wave * 20 + 10 + o] = rq; }
    }
    __syncthreads();
    if (tid < 20) {
        float t = sPart[tid] + sPart[20 + tid] + sPart[40 + tid] + sPart[60 + tid];
        atomicAdd(&stats2[tid], t);
    }
}

// Kernel E: finalize BN2, comp_full = ReLU(BN2(y2)), node1 = GRU1(comp_full, f1)
__global__ __launch_bounds__(256) void kernE(
    const float* __restrict__ f1, const float* __restrict__ y2in,
    const float* __restrict__ stats2,
    const float* __restrict__ g_r2, const float* __restrict__ be_r2,
    const float* __restrict__ Wg1, const float* __restrict__ bg1, const float* __restrict__ Wc1,
    float* __restrict__ node1)
{
    __shared__ float sWg[40], sWc[200], sA[10], sB[10];
    const int tid = threadIdx.x;
    for (int i = tid; i < 200; i += 256) sWc[i] = Wc1[i];
    if (tid < 40) sWg[tid] = Wg1[tid];
    if (tid < 10) {
        float sm = stats2[tid], sq = stats2[10 + tid];
        float mean = sm * (1.0f / BN_N);
        float var = sq * (1.0f / BN_N) - mean * mean;
        float a = g_r2[tid] * rsqrtf(var + EPS_BN);
        sA[tid] = a;
        sB[tid] = be_r2[tid] - mean * a;
    }
    __syncthreads();
    const float bg_r = bg1[0], bg_u = bg1[1];
    const int p = blockIdx.x * 256 + tid;
    const int b = p >> 14, s = p & 16383;
    const int base = b * (CDIM * HW) + s;

    float comp[10], vf1[10];
#pragma unroll
    for (int c = 0; c < 10; c++) {
        vf1[c] = f1[base + c * HW];
        comp[c] = fmaxf(fmaf(sA[c], y2in[base + c * HW], sB[c]), 0.0f);
    }
    float g0 = bg_r, g1 = bg_u;
#pragma unroll
    for (int i = 0; i < 10; i++) {
        g0 += sWg[i] * comp[i] + sWg[10 + i] * vf1[i];
        g1 += sWg[20 + i] * comp[i] + sWg[30 + i] * vf1[i];
    }
    const float r = sigf(g0), u = sigf(g1);
#pragma unroll
    for (int o = 0; o < 10; o++) {
        float acc = 0.0f;
#pragma unroll
        for (int i = 0; i < 10; i++) acc = fmaf(sWc[o * 20 + i], comp[i], acc);
#pragma unroll
        for (int i = 0; i < 10; i++) acc = fmaf(sWc[o * 20 + 10 + i], r * vf1[i], acc);
        node1[base + o * HW] = (1.0f - u) * vf1[o] + u * tanh_fast(acc);
    }
}

extern "C" void kernel_launch(void* const* d_in, const int* in_sizes, int n_in,
                              void* d_out, int out_size, void* d_ws, size_t ws_size,
                              hipStream_t stream) {
    const float* f0    = (const float*)d_in[0];
    const float* f1    = (const float*)d_in[1];
    const float* h0    = (const float*)d_in[2];
    const float* h1    = (const float*)d_in[3];
    const float* h2    = (const float*)d_in[4];
    const float* W_att = (const float*)d_in[5];
    const float* b_att = (const float*)d_in[6];
    const float* W_r1  = (const float*)d_in[7];
    const float* g_r1  = (const float*)d_in[8];
    const float* be_r1 = (const float*)d_in[9];
    const float* W_r2  = (const float*)d_in[10];
    const float* g_r2  = (const float*)d_in[11];
    const float* be_r2 = (const float*)d_in[12];
    const float* Wg0   = (const float*)d_in[13];
    const float* bg0   = (const float*)d_in[14];
    const float* Wc0   = (const float*)d_in[15];
    const float* Wg1   = (const float*)d_in[16];
    const float* bg1   = (const float*)d_in[17];
    const float* Wc1   = (const float*)d_in[18];

    float* out   = (float*)d_out;
    float* node0 = out;
    float* node1 = out + NPLANE;
    float* attO  = out + 2 * NPLANE;

    float* y2     = (float*)d_ws;                 // NPIX*10 floats
    float* stats1 = y2 + (size_t)10 * NPIX;       // 40 floats
    float* stats2 = stats1 + 40;                  // 20 floats

    hipMemsetAsync(stats1, 0, 64 * sizeof(float), stream);

    dim3 grid(NPIX / 256), blk(256);
    kernA<<<grid, blk, 0, stream>>>(f0, f1, h0, h1, h2, W_att, b_att, W_r1,
                                    Wg0, bg0, Wc0, node0, attO, stats1);
    kernC<<<grid, blk, 0, stream>>>(f1, h1, h2, attO, W_r1, g_r1, be_r1, W_r2,
                                    stats1, y2, stats2);
    kernE<<<grid, blk, 0, stream>>>(f1, y2, stats2, g_r2, be_r2, Wg1, bg1, Wc1,
                                    node1);
}